// Round 11
// baseline (494.445 us; speedup 1.0000x reference)
//
#include <hip/hip_runtime.h>
#include <hip/hip_fp16.h>

// Problem constants (fixed by the reference)
constexpr int NN = 100000;          // nodes
constexpr int EE = 1600000;         // edges (without self loops)
constexpr int ET = EE + NN;         // edges + self loops
constexpr int EQ = EE / 4;          // 400000 int4 groups of real edges
constexpr int TQ = ET / 4;          // 425000 int4 groups total (ET % 4 == 0)
constexpr int NBUK = (NN + 255) / 256;  // 391 dst-buckets of 256 nodes
constexpr int PB = 416;             // blocks for bucket count/place
constexpr int GB = (NN + 127) / 128;    // 782 MFMA gemm blocks
constexpr float NEG = 0.2f;

typedef _Float16 f16x8 __attribute__((ext_vector_type(8)));
typedef float    f32x4 __attribute__((ext_vector_type(4)));

// ---------------------------------------------------------------------------
// Device bodies for the fused front-end kernels.
// ---------------------------------------------------------------------------
__device__ __forceinline__ void wprep_dev(int bx, const float* __restrict__ W1, const float* __restrict__ W2,
                                          _Float16* __restrict__ w1T, _Float16* __restrict__ w2T) {
    int idx = bx * 256 + threadIdx.x;
    if (idx < 128 * 128) {
        int nn = idx >> 7, k = idx & 127;
        w1T[idx] = (_Float16)W1[k * 128 + nn];
    }
    int i2 = idx - 128 * 128;
    if (i2 >= 0 && i2 < 64 * 256) {
        int nn = i2 >> 8, k = i2 & 255;
        w2T[i2] = (_Float16)W2[k * 64 + nn];
    }
}

__device__ __forceinline__ void bcount_dev(int bx, const int4* __restrict__ dst4v,
                                           int* __restrict__ bucketCount) {
    __shared__ int bh[NBUK];
    for (int i = threadIdx.x; i < NBUK; i += 256) bh[i] = 0;
    __syncthreads();
    int gtid = bx * 256 + threadIdx.x;
    for (int q = gtid; q < TQ; q += PB * 256) {
        int4 d;
        if (q < EQ) {
            d = dst4v[q];
        } else {
            int s0 = (q - EQ) * 4;       // self loops: dst = node id
            d.x = s0; d.y = s0 + 1; d.z = s0 + 2; d.w = s0 + 3;
        }
        atomicAdd(&bh[d.x >> 8], 1);
        atomicAdd(&bh[d.y >> 8], 1);
        atomicAdd(&bh[d.z >> 8], 1);
        atomicAdd(&bh[d.w >> 8], 1);
    }
    __syncthreads();
    for (int i = threadIdx.x; i < NBUK; i += 256)
        if (bh[i]) atomicAdd(&bucketCount[i], bh[i]);
}

__device__ __forceinline__ void bplace_dev(int bx, const int4* __restrict__ src4v, const int4* __restrict__ dst4v,
                                           int* __restrict__ gcur, unsigned int* __restrict__ ebuf) {
    __shared__ int bh[NBUK];
    __shared__ int bbase[NBUK];
    for (int i = threadIdx.x; i < NBUK; i += 256) bh[i] = 0;
    __syncthreads();
    int gtid = bx * 256 + threadIdx.x;

    int esrc[16];
    int emeta[16];   // (b<<21) | (ldst<<13) | lrank
#pragma unroll
    for (int it = 0; it < 4; it++) {
        int q = gtid + it * (PB * 256);
        bool valid = q < TQ;
        int4 s, d;
        if (valid) {
            if (q < EQ) { s = src4v[q]; d = dst4v[q]; }
            else { int s0 = (q - EQ) * 4; s.x = s0; s.y = s0 + 1; s.z = s0 + 2; s.w = s0 + 3; d = s; }
        } else {
            s.x = s.y = s.z = s.w = 0; d = s;
        }
        int ss[4] = {s.x, s.y, s.z, s.w};
        int dd[4] = {d.x, d.y, d.z, d.w};
#pragma unroll
        for (int k = 0; k < 4; k++) {
            int idx = it * 4 + k;
            if (valid) {
                int b = dd[k] >> 8, l = dd[k] & 255;
                int r = atomicAdd(&bh[b], 1);
                esrc[idx]  = ss[k];
                emeta[idx] = (b << 21) | (l << 13) | r;
            } else {
                emeta[idx] = -1;
            }
        }
    }
    __syncthreads();
    for (int i = threadIdx.x; i < NBUK; i += 256)
        bbase[i] = bh[i] ? atomicAdd(&gcur[i], bh[i]) : 0;
    __syncthreads();
#pragma unroll
    for (int e = 0; e < 16; e++) {
        int me = emeta[e];
        if (me >= 0) {
            int b = me >> 21, l = (me >> 13) & 255, r = me & 8191;
            ebuf[bbase[b] + r] = ((unsigned)l << 24) | (unsigned)esrc[e];
        }
    }
}

// ---------------------------------------------------------------------------
// LDS-free direct MFMA GEMM body (device fn). See R8/R10 notes.
// ---------------------------------------------------------------------------
template <int K, int C, bool SRCF32, int AMODE, int OUTM, int SET>
__device__ __forceinline__ void gemm_dev(int bx, const void* __restrict__ xv,
                                         const _Float16* __restrict__ wT,
                                         const float* __restrict__ as_w, const float* __restrict__ ad_w,
                                         __half* __restrict__ xp,
                                         float* __restrict__ att_s, float* __restrict__ att_d, int n) {
    constexpr int NT = C / 16;       // 16-col tiles
    const int tid  = threadIdx.x;
    const int w    = tid >> 6;
    const int lane = tid & 63;
    const int quad = lane >> 4;
    const int l16  = lane & 15;
    const long r0  = (long)bx * 128;
    const long row0 = r0 + w * 32 + l16;       // a0 fragment row
    const long row1 = row0 + 16;               // a1 fragment row

    f32x4 acc[2][NT];
#pragma unroll
    for (int s = 0; s < 2; s++)
#pragma unroll
        for (int t = 0; t < NT; t++) acc[s][t] = (f32x4){0.f, 0.f, 0.f, 0.f};

#pragma unroll
    for (int ks = 0; ks < K; ks += 32) {
        f16x8 a0 = (f16x8){0, 0, 0, 0, 0, 0, 0, 0};
        f16x8 a1 = (f16x8){0, 0, 0, 0, 0, 0, 0, 0};
        if (SRCF32) {
            if (row0 < n) {
                const float4* p = (const float4*)((const float*)xv + row0 * K + ks) + quad * 2;
                float4 u = p[0], v = p[1];
                a0 = (f16x8){(_Float16)u.x, (_Float16)u.y, (_Float16)u.z, (_Float16)u.w,
                             (_Float16)v.x, (_Float16)v.y, (_Float16)v.z, (_Float16)v.w};
            }
            if (row1 < n) {
                const float4* p = (const float4*)((const float*)xv + row1 * K + ks) + quad * 2;
                float4 u = p[0], v = p[1];
                a1 = (f16x8){(_Float16)u.x, (_Float16)u.y, (_Float16)u.z, (_Float16)u.w,
                             (_Float16)v.x, (_Float16)v.y, (_Float16)v.z, (_Float16)v.w};
            }
        } else {
            if (row0 < n) a0 = *(const f16x8*)((const _Float16*)xv + row0 * K + ks + quad * 8);
            if (row1 < n) a1 = *(const f16x8*)((const _Float16*)xv + row1 * K + ks + quad * 8);
        }
#pragma unroll
        for (int t = 0; t < NT; t++) {
            f16x8 b = *(const f16x8*)(wT + (long)(t * 16 + l16) * K + ks + quad * 8);
            acc[0][t] = __builtin_amdgcn_mfma_f32_16x16x32_f16(a0, b, acc[0][t], 0, 0, 0);
            acc[1][t] = __builtin_amdgcn_mfma_f32_16x16x32_f16(a1, b, acc[1][t], 0, 0, 0);
        }
    }

    // xp write: C/D layout col = l16 (within tile), row = quad*4+rg
#pragma unroll
    for (int sub = 0; sub < 2; sub++) {
        long rb = r0 + w * 32 + sub * 16 + quad * 4;
#pragma unroll
        for (int t = 0; t < NT; t++) {
            int c = t * 16 + l16;
#pragma unroll
            for (int rg = 0; rg < 4; rg++) {
                long row = rb + rg;
                if (row < n) {
                    __half hv = __float2half(acc[sub][t][rg]);
                    if (OUTM == 0)
                        xp[row * 256 + ((c >> 1) << 2) + (c & 1) + SET * 2] = hv;
                    else
                        xp[row * (long)C + c] = hv;
                }
            }
        }
    }

    if (AMODE == 1) {
        // 4 heads x 32 ch; col c = t*16+l16 -> head t>>1.
        float asw[8], adw[8];
#pragma unroll
        for (int t = 0; t < 8; t++) {
            int ci = (t >> 1) * 32 + (t & 1) * 16 + l16;
            asw[t] = as_w[ci];
            adw[t] = ad_w[ci];
        }
#pragma unroll
        for (int sub = 0; sub < 2; sub++) {
#pragma unroll
            for (int rg = 0; rg < 4; rg++) {
                long row = r0 + w * 32 + sub * 16 + quad * 4 + rg;
                float hs[4] = {0.f, 0.f, 0.f, 0.f};
                float hd[4] = {0.f, 0.f, 0.f, 0.f};
#pragma unroll
                for (int t = 0; t < 8; t++) {
                    float av = acc[sub][t][rg];
                    hs[t >> 1] += av * asw[t];
                    hd[t >> 1] += av * adw[t];
                }
#pragma unroll
                for (int h = 0; h < 4; h++) {
                    hs[h] += __shfl_xor(hs[h], 1); hs[h] += __shfl_xor(hs[h], 2);
                    hs[h] += __shfl_xor(hs[h], 4); hs[h] += __shfl_xor(hs[h], 8);
                    hd[h] += __shfl_xor(hd[h], 1); hd[h] += __shfl_xor(hd[h], 2);
                    hd[h] += __shfl_xor(hd[h], 4); hd[h] += __shfl_xor(hd[h], 8);
                }
                if (l16 == 0 && row < n) {
#pragma unroll
                    for (int h = 0; h < 4; h++) {
                        att_s[row * 8 + h * 2 + SET] = hs[h];
                        att_d[row * 8 + h * 2 + SET] = hd[h];
                    }
                }
            }
        }
    }
    if (AMODE == 2) {
        float asw[NT], adw[NT];
#pragma unroll
        for (int t = 0; t < NT; t++) {
            asw[t] = as_w[t * 16 + l16];
            adw[t] = ad_w[t * 16 + l16];
        }
#pragma unroll
        for (int sub = 0; sub < 2; sub++) {
#pragma unroll
            for (int rg = 0; rg < 4; rg++) {
                long row = r0 + w * 32 + sub * 16 + quad * 4 + rg;
                float s = 0.f, d = 0.f;
#pragma unroll
                for (int t = 0; t < NT; t++) {
                    float av = acc[sub][t][rg];
                    s += av * asw[t];
                    d += av * adw[t];
                }
                s += __shfl_xor(s, 1); s += __shfl_xor(s, 2); s += __shfl_xor(s, 4); s += __shfl_xor(s, 8);
                d += __shfl_xor(d, 1); d += __shfl_xor(d, 2); d += __shfl_xor(d, 4); d += __shfl_xor(d, 8);
                if (l16 == 0 && row < n) {
                    att_s[row] = s;
                    att_d[row] = d;
                }
            }
        }
    }
}

// ---------------------------------------------------------------------------
// mega0: one-time weight prep + bucket count (independent work, one launch).
// bucketCount is zeroed by hipMemsetAsync beforehand (no intra-kernel race).
// ---------------------------------------------------------------------------
__global__ __launch_bounds__(256) void mega0(const float* __restrict__ W1, const float* __restrict__ W2,
                                             _Float16* __restrict__ w1T, _Float16* __restrict__ w2T,
                                             const int4* __restrict__ dst4v, int* __restrict__ bucketCount) {
    int bx = blockIdx.x;
    if (bx < 128) wprep_dev(bx, W1, W2, w1T, w2T);
    else          bcount_dev(bx - 128, dst4v, bucketCount);
}

// ---------------------------------------------------------------------------
// megaA2: fused {gemm_p, gemm_g, bplace}. bplace (latency-bound, ~35us) hides
// behind the two GEMMs (grid-partitioned; bscan already done).
// ---------------------------------------------------------------------------
__global__ __launch_bounds__(256) void megaA2(const float* __restrict__ x_ppi, const float* __restrict__ x_go,
                                              const int4* __restrict__ src4v, const int4* __restrict__ dst4v,
                                              const _Float16* __restrict__ w1T,
                                              const float* __restrict__ as1, const float* __restrict__ ad1,
                                              __half* __restrict__ xpc,
                                              float* __restrict__ att1s, float* __restrict__ att1d,
                                              int* __restrict__ gcur, unsigned int* __restrict__ ebuf) {
    int bx = blockIdx.x;
    if (bx < GB) {
        gemm_dev<128, 128, true, 1, 0, 0>(bx, x_ppi, w1T, as1, ad1, xpc, att1s, att1d, NN);
    } else if (bx < 2 * GB) {
        gemm_dev<128, 128, true, 1, 0, 1>(bx - GB, x_go, w1T, as1, ad1, xpc, att1s, att1d, NN);
    } else {
        bplace_dev(bx - 2 * GB, src4v, dst4v, gcur, ebuf);
    }
}

__global__ __launch_bounds__(256) void gemm_k2(const __half* __restrict__ hbuf,
                                               const _Float16* __restrict__ w2T,
                                               const float* __restrict__ as2, const float* __restrict__ ad2,
                                               __half* __restrict__ xp2,
                                               float* __restrict__ asr2, float* __restrict__ ads2) {
    gemm_dev<256, 64, false, 2, 1, 0>(blockIdx.x, hbuf, w2T, as2, ad2, xp2, asr2, ads2, NN);
}

// ---------------------------------------------------------------------------
// CSR build rest: bscan -> (bplace in megaA2) -> per-bucket csr.
// ---------------------------------------------------------------------------
__global__ __launch_bounds__(512) void k_bscan(const int* __restrict__ bucketCount,
                                               int* __restrict__ bstart, int* __restrict__ gcur,
                                               int* __restrict__ rs) {
    __shared__ int sh[512];
    int t = threadIdx.x;
    int v = (t < NBUK) ? bucketCount[t] : 0;
    sh[t] = v;
    __syncthreads();
    for (int o = 1; o < 512; o <<= 1) {
        int u = (t >= o) ? sh[t - o] : 0;
        __syncthreads();
        sh[t] += u;
        __syncthreads();
    }
    if (t < NBUK) { bstart[t] = sh[t] - v; gcur[t] = sh[t] - v; }
    if (t == 0) { bstart[NBUK] = ET; rs[NN] = ET; }
}

__global__ __launch_bounds__(256) void k_csr(const unsigned int* __restrict__ ebuf,
                                             const int* __restrict__ bstart,
                                             int* __restrict__ rs, int* __restrict__ csr) {
    __shared__ int hist[256];
    __shared__ int sh[256];
    __shared__ int cur[256];
    int b = blockIdx.x;
    int t = threadIdx.x;
    int e0 = bstart[b], e1 = bstart[b + 1];
    hist[t] = 0;
    __syncthreads();
    for (int j = e0 + t; j < e1; j += 256)
        atomicAdd(&hist[ebuf[j] >> 24], 1);
    __syncthreads();
    int v = hist[t];
    sh[t] = v;
    __syncthreads();
    for (int o = 1; o < 256; o <<= 1) {
        int u = (t >= o) ? sh[t - o] : 0;
        __syncthreads();
        sh[t] += u;
        __syncthreads();
    }
    int excl = sh[t] - v;
    cur[t] = excl;
    int v0 = b * 256;
    if (v0 + t < NN) rs[v0 + t] = e0 + excl;
    __syncthreads();
    for (int j = e0 + t; j < e1; j += 256) {
        unsigned int e = ebuf[j];
        int l = (int)(e >> 24);
        int r = atomicAdd(&cur[l], 1);
        csr[e0 + r] = (int)(e & 0x00FFFFFFu);
    }
}

// ---------------------------------------------------------------------------
// k_sortadj: sort each node's adjacency slice csr[e0:e1] ascending by src.
// One 64-lane wave per node; shfl-based bitonic sort of 64 elems (pad MAX).
// deg>64 (vanishingly rare at Poisson(17)): sort only the first 64 - still a
// permutation of those elems, correctness preserved (sum is order-free).
// Purpose: waves sweep src-space monotonically -> cohort accesses cluster in
// a moving window (L2 retention) and the miss stream becomes ascending
// (DRAM row locality). Purely a performance transform.
// ---------------------------------------------------------------------------
__global__ __launch_bounds__(256) void k_sortadj(const int* __restrict__ rs, int* __restrict__ csr) {
    int v = blockIdx.x * 4 + (threadIdx.x >> 6);
    if (v >= NN) return;
    int lane = threadIdx.x & 63;
    int e0 = rs[v], e1 = rs[v + 1];
    int deg = e1 - e0;
    int nsort = (deg < 64) ? deg : 64;
    int val = (lane < nsort) ? csr[e0 + lane] : 0x7FFFFFFF;
#pragma unroll
    for (int k = 2; k <= 64; k <<= 1) {
#pragma unroll
        for (int j = k >> 1; j >= 1; j >>= 1) {
            int other = __shfl_xor(val, j);
            bool up = ((lane & k) == 0);
            bool lower = ((lane & j) == 0);
            bool keepMin = (up == lower);
            int mn = (val < other) ? val : other;
            int mx = (val < other) ? other : val;
            val = keepMin ? mn : mx;
        }
    }
    if (lane < nsort) csr[e0 + lane] = val;
}

// ---------------------------------------------------------------------------
// Packed single-pass conv1. One wave per dst node; two 32-lane halves each
// take edges j+2q+h; lane m (0..31) gathers the full 512B packed row via
// uint4. Attention weights inline from float2 tables. 8-edge full chunks
// (4 gathers in flight), 2-edge clamped tail. Cross-half shfl_xor combine.
// ---------------------------------------------------------------------------
__global__ __launch_bounds__(256) void conv1_packed(const int* __restrict__ rs, const int* __restrict__ csr,
                                                    const uint4* __restrict__ xpc,
                                                    const float2* __restrict__ att_s,  // [NN*4] {p,g}
                                                    const float2* __restrict__ att_d,  // [NN*4] {p,g}
                                                    const float* __restrict__ bias,
                                                    __half* __restrict__ out) {
    int v = blockIdx.x * 4 + (threadIdx.x >> 6);
    if (v >= NN) return;
    int lane = threadIdx.x & 63;
    int h = lane >> 5;                 // half-wave: 0 -> even edges, 1 -> odd edges
    int m = lane & 31;                 // channels 4m..4m+3 of both sets
    int hd = m >> 3;                   // head index
    int e0 = rs[v], e1 = rs[v + 1];

    float2 ad = att_d[v * 4 + hd];
    auto lrexp = [](float e) { e = (e > 0.f) ? e : NEG * e; return __expf(e); };

    float ap0 = 0.f, ap1 = 0.f, ap2 = 0.f, ap3 = 0.f;
    float ag0 = 0.f, ag1 = 0.f, ag2 = 0.f, ag3 = 0.f;
    float dp = 0.f, dg = 0.f;

    int j = e0;
    // full chunks: 8 edges, 4 gathers in flight, no predication
    for (; j + 8 <= e1; j += 8) {
        int s[4]; float2 av[4]; uint4 r[4];
#pragma unroll
        for (int q = 0; q < 4; q++) s[q] = csr[j + 2 * q + h];
#pragma unroll
        for (int q = 0; q < 4; q++) av[q] = att_s[s[q] * 4 + hd];
#pragma unroll
        for (int q = 0; q < 4; q++) r[q] = xpc[(long)s[q] * 32 + m];
#pragma unroll
        for (int q = 0; q < 4; q++) {
            float wx = lrexp(av[q].x + ad.x);
            float wy = lrexp(av[q].y + ad.y);
            dp += wx; dg += wy;
            float2 p01 = __half22float2(*(__half2*)&r[q].x);
            float2 g01 = __half22float2(*(__half2*)&r[q].y);
            float2 p23 = __half22float2(*(__half2*)&r[q].z);
            float2 g23 = __half22float2(*(__half2*)&r[q].w);
            ap0 += wx * p01.x; ap1 += wx * p01.y; ap2 += wx * p23.x; ap3 += wx * p23.y;
            ag0 += wy * g01.x; ag1 += wy * g01.y; ag2 += wy * g23.x; ag3 += wy * g23.y;
        }
    }
    // tail: 2 edges per iteration, clamped duplicate gathers with zero weight
    for (; j < e1; j += 2) {
        int jj = j + h;
        int jc = (jj < e1) ? jj : (e1 - 1);
        bool ok = jj < e1;
        int s = csr[jc];
        float2 av = att_s[s * 4 + hd];
        uint4 r = xpc[(long)s * 32 + m];
        float wx = ok ? lrexp(av.x + ad.x) : 0.f;
        float wy = ok ? lrexp(av.y + ad.y) : 0.f;
        dp += wx; dg += wy;
        float2 p01 = __half22float2(*(__half2*)&r.x);
        float2 g01 = __half22float2(*(__half2*)&r.y);
        float2 p23 = __half22float2(*(__half2*)&r.z);
        float2 g23 = __half22float2(*(__half2*)&r.w);
        ap0 += wx * p01.x; ap1 += wx * p01.y; ap2 += wx * p23.x; ap3 += wx * p23.y;
        ag0 += wy * g01.x; ag1 += wy * g01.y; ag2 += wy * g23.x; ag3 += wy * g23.y;
    }

    // combine the two halves (independent edge subsets)
    ap0 += __shfl_xor(ap0, 32); ap1 += __shfl_xor(ap1, 32);
    ap2 += __shfl_xor(ap2, 32); ap3 += __shfl_xor(ap3, 32);
    ag0 += __shfl_xor(ag0, 32); ag1 += __shfl_xor(ag1, 32);
    ag2 += __shfl_xor(ag2, 32); ag3 += __shfl_xor(ag3, 32);
    dp  += __shfl_xor(dp, 32);  dg  += __shfl_xor(dg, 32);

    float ivp = 1.0f / dp, ivg = 1.0f / dg;
    int c0 = 4 * m;
    float4 b4 = *(const float4*)&bias[c0];
    // half 0 writes the p-set, half 1 writes the g-set (same channels)
    float inv = h ? ivg : ivp;
    float a0 = h ? ag0 : ap0;
    float a1 = h ? ag1 : ap1;
    float a2 = h ? ag2 : ap2;
    float a3 = h ? ag3 : ap3;
    __half2 o01 = __floats2half2_rn(fmaxf(a0 * inv + b4.x, 0.f), fmaxf(a1 * inv + b4.y, 0.f));
    __half2 o23 = __floats2half2_rn(fmaxf(a2 * inv + b4.z, 0.f), fmaxf(a3 * inv + b4.w, 0.f));
    uint2 st;
    st.x = *(unsigned int*)&o01;
    st.y = *(unsigned int*)&o23;
    *(uint2*)(out + (long)v * 256 + h * 128 + c0) = st;
}

// ---------------------------------------------------------------------------
// Single-pass conv2 edge kernel (H=1, C=64, fp16 xp). Weight inline from
// asrc[s] (400KB) + adst[v] register. Quarter-waves; 16-edge full chunks.
// ---------------------------------------------------------------------------
__global__ __launch_bounds__(256) void conv2_edge(const int* __restrict__ rs, const int* __restrict__ csr,
                                                  const __half* __restrict__ xp,
                                                  const float* __restrict__ asrc,
                                                  const float* __restrict__ adst,
                                                  const float* __restrict__ bias,
                                                  float* __restrict__ out) {
    int v = blockIdx.x * 4 + (threadIdx.x >> 6);
    if (v >= NN) return;
    int lane = threadIdx.x & 63;
    int qw = lane >> 4;                // quarter-wave: edge offset
    int m = lane & 15;                 // channels 4m..4m+3
    int e0 = rs[v], e1 = rs[v + 1];
    const uint2* xp2 = (const uint2*)xp;

    float adv = adst[v];
    auto lrexp = [](float e) { e = (e > 0.f) ? e : NEG * e; return __expf(e); };

    float a0 = 0.f, a1 = 0.f, a2 = 0.f, a3 = 0.f, d = 0.f;

    int j = e0;
    // full chunks: 16 edges, 4 gathers in flight, no predication
    for (; j + 16 <= e1; j += 16) {
        int s[4]; float av[4]; uint2 r[4];
#pragma unroll
        for (int k = 0; k < 4; k++) s[k] = csr[j + 4 * k + qw];
#pragma unroll
        for (int k = 0; k < 4; k++) av[k] = asrc[s[k]];
#pragma unroll
        for (int k = 0; k < 4; k++) r[k] = xp2[(long)s[k] * 16 + m];
#pragma unroll
        for (int k = 0; k < 4; k++) {
            float w = lrexp(av[k] + adv);
            d += w;
            float2 x01 = __half22float2(*(__half2*)&r[k].x);
            float2 x23 = __half22float2(*(__half2*)&r[k].y);
            a0 += w * x01.x; a1 += w * x01.y;
            a2 += w * x23.x; a3 += w * x23.y;
        }
    }
    // tail: 4 edges per iteration, clamped
    for (; j < e1; j += 4) {
        int jj = j + qw;
        int jc = (jj < e1) ? jj : (e1 - 1);
        int s = csr[jc];
        float av = asrc[s];
        uint2 r = xp2[(long)s * 16 + m];
        float w = (jj < e1) ? lrexp(av + adv) : 0.f;
        d += w;
        float2 x01 = __half22float2(*(__half2*)&r.x);
        float2 x23 = __half22float2(*(__half2*)&r.y);
        a0 += w * x01.x; a1 += w * x01.y;
        a2 += w * x23.x; a3 += w * x23.y;
    }

    // combine the four quarters
    a0 += __shfl_xor(a0, 16); a1 += __shfl_xor(a1, 16);
    a2 += __shfl_xor(a2, 16); a3 += __shfl_xor(a3, 16);
    d  += __shfl_xor(d, 16);
    a0 += __shfl_xor(a0, 32); a1 += __shfl_xor(a1, 32);
    a2 += __shfl_xor(a2, 32); a3 += __shfl_xor(a3, 32);
    d  += __shfl_xor(d, 32);

    if (qw == 0) {
        float inv = 1.0f / d;
        float4 b4 = *(const float4*)&bias[4 * m];
        float4 o;
        o.x = a0 * inv + b4.x;
        o.y = a1 * inv + b4.y;
        o.z = a2 * inv + b4.z;
        o.w = a3 * inv + b4.w;
        *(float4*)&out[(long)v * 64 + 4 * m] = o;
    }
}

// ---------------------------------------------------------------------------
// Launch
// ---------------------------------------------------------------------------
extern "C" void kernel_launch(void* const* d_in, const int* in_sizes, int n_in,
                              void* d_out, int out_size, void* d_ws, size_t ws_size,
                              hipStream_t stream) {
    const float* x_ppi = (const float*)d_in[0];
    const float* x_go  = (const float*)d_in[1];
    const int*   ei    = (const int*)d_in[2];
    const float* W1    = (const float*)d_in[3];
    const float* as1   = (const float*)d_in[4];
    const float* ad1   = (const float*)d_in[5];
    const float* b1    = (const float*)d_in[6];
    const float* W2    = (const float*)d_in[7];
    const float* as2   = (const float*)d_in[8];
    const float* ad2   = (const float*)d_in[9];
    const float* b2    = (const float*)d_in[10];
    float* out = (float*)d_out;

    char* ws = (char*)d_ws;
    size_t off = 0;
    auto alloc = [&](size_t bytes) -> void* {
        void* p = ws + off;
        off = (off + bytes + 255) & ~(size_t)255;
        return p;
    };
    int* bucketCount = (int*)alloc((size_t)NBUK * 4);
    int* bstart      = (int*)alloc((size_t)(NBUK + 1) * 4);
    int* gcur        = (int*)alloc((size_t)NBUK * 4);
    unsigned int* ebuf = (unsigned int*)alloc((size_t)ET * 4);
    int* rs      = (int*)alloc((size_t)(NN + 1) * 4);
    int* csr     = (int*)alloc((size_t)ET * 4);
    _Float16* w1T = (_Float16*)alloc((size_t)128 * 128 * 2);
    _Float16* w2T = (_Float16*)alloc((size_t)64 * 256 * 2);
    __half* xpc  = (__half*)alloc((size_t)NN * 256 * 2);   // packed {p0,p1,g0,g1} fp16
    __half* xp2  = (__half*)alloc((size_t)NN * 64 * 2);    // conv2 features fp16
    float* att1s = (float*)alloc((size_t)NN * 4 * 8);      // float2 {p,g} per (node,head)
    float* att1d = (float*)alloc((size_t)NN * 4 * 8);
    float* asr2  = (float*)alloc((size_t)NN * 4);
    float* ads2  = (float*)alloc((size_t)NN * 4);
    __half* hbuf = (__half*)alloc((size_t)NN * 256 * 2);   // conv1 output, fp16
    (void)ws_size; (void)in_sizes; (void)n_in; (void)out_size;

    // 1) zero bucket counters, then fused {weight prep + bucket count}
    hipMemsetAsync(bucketCount, 0, (size_t)NBUK * 4, stream);
    mega0<<<128 + PB, 256, 0, stream>>>(W1, W2, w1T, w2T, (const int4*)(ei + EE), bucketCount);
    // 2) bucket scan
    k_bscan<<<1, 512, 0, stream>>>(bucketCount, bstart, gcur, rs);
    // 3) fused {gemm_p + gemm_g + bplace} -- bplace hides behind the GEMMs
    megaA2<<<2 * GB + PB, 256, 0, stream>>>(x_ppi, x_go, (const int4*)ei, (const int4*)(ei + EE),
                                            w1T, as1, ad1, xpc, att1s, att1d, gcur, ebuf);
    // 4) per-bucket CSR finalize
    k_csr<<<NBUK, 256, 0, stream>>>(ebuf, bstart, rs, csr);
    // 5) sort each node's adjacency by src (locality transform)
    k_sortadj<<<NN / 4, 256, 0, stream>>>(rs, csr);
    // 6) packed single-pass conv1 with inline attention
    conv1_packed<<<NN / 4, 256, 0, stream>>>(rs, csr, (const uint4*)xpc,
                                             (const float2*)att1s, (const float2*)att1d, b1, hbuf);
    // 7) layer-2 GEMM with fused H=1 attention
    gemm_k2<<<GB, 256, 0, stream>>>(hbuf, w2T, as2, ad2, xp2, asr2, ads2);
    // 8) conv2
    conv2_edge<<<NN / 4, 256, 0, stream>>>(rs, csr, xp2, asr2, ads2, b2, out);
}